// Round 21
// baseline (276.416 us; speedup 1.0000x reference)
//
#include <hip/hip_runtime.h>

typedef __attribute__((ext_vector_type(8))) short bf16x8;
typedef __attribute__((ext_vector_type(4))) float f32x4;

#define NB 512   // grid size; exactly 2 blocks/CU on 256 CUs

// ---------- helpers ----------

__device__ __forceinline__ unsigned short f2bf(float f) {
    unsigned int u = __builtin_bit_cast(unsigned int, f);
    u += 0x7fffu + ((u >> 16) & 1u);
    return (unsigned short)(u >> 16);
}

__device__ __forceinline__ float bf2f(unsigned short s) {
    return __builtin_bit_cast(float, (unsigned int)s << 16);
}

__device__ __forceinline__ void g2lds16(const unsigned short* g, unsigned short* l) {
    __builtin_amdgcn_global_load_lds(
        (const __attribute__((address_space(1))) unsigned int*)g,
        (__attribute__((address_space(3))) unsigned int*)l, 16, 0, 0);
}

// grid barrier: one arrival counter per phase boundary (zeroed via memset each
// call). All NB blocks are co-resident (2/CU, enforced by 64KB LDS +
// launch_bounds). Agent-scope fences handle cross-XCD L2 visibility.
__device__ __forceinline__ void gbar(int* cnt) {
    __syncthreads();
    if (threadIdx.x == 0) {
        __threadfence();   // agent release: L2 writeback
        __hip_atomic_fetch_add(cnt, 1, __ATOMIC_ACQ_REL, __HIP_MEMORY_SCOPE_AGENT);
        while (__hip_atomic_load(cnt, __ATOMIC_ACQUIRE, __HIP_MEMORY_SCOPE_AGENT) < NB)
            __builtin_amdgcn_s_sleep(4);
        __threadfence();   // agent acquire: L2 invalidate
    }
    __syncthreads();
}

// ---------- fused: prep | barrier | qk GEMM | barrier | attn GEMM | barrier | scale ----------

__global__ __launch_bounds__(256, 2)
void fused_kernel(const float* __restrict__ x, const float* __restrict__ Wq_,
                  const float* __restrict__ Wk_, const float* __restrict__ Wv,
                  const float* __restrict__ bv, const float* __restrict__ bq,
                  const float* __restrict__ bk, const float* __restrict__ gammap,
                  unsigned short* __restrict__ xb, unsigned short* __restrict__ wqk,
                  unsigned short* __restrict__ qb, unsigned short* __restrict__ kb,
                  float* __restrict__ vd, float* __restrict__ dpart,
                  float* __restrict__ out, int* __restrict__ bar,
                  int M, int n4w) {
    __shared__ __align__(16) char smem[65536];
    const int tid = threadIdx.x;
    const int bid = blockIdx.x;
    const int lane = tid & 63;
    const int K = 1024;
    unsigned short* nmb = xb;   // xb dead after qk phase; reuse for bf16 num'

    // ================= phase A: pack x/Wq/Wk -> bf16, fused vdiag =================
    {
        float* red = (float*)smem;
        const int total = M + 2 * n4w / 256;   // 6144
        for (int vb = bid; vb < total; vb += NB) {
            if (vb < M) {
                const int row = vb;            // b*1024 + j
                const int j = row & 1023;
                const int e4 = row * 256 + tid;
                float4 v = reinterpret_cast<const float4*>(x)[e4];
                union { unsigned short s4[4]; uint2 u; } o;
                o.s4[0] = f2bf(v.x); o.s4[1] = f2bf(v.y); o.s4[2] = f2bf(v.z); o.s4[3] = f2bf(v.w);
                reinterpret_cast<uint2*>(xb)[e4] = o.u;

                float4 w = reinterpret_cast<const float4*>(Wv + (size_t)j * 1024)[tid];
                float s = v.x * w.x + v.y * w.y + v.z * w.z + v.w * w.w;
                #pragma unroll
                for (int off = 32; off; off >>= 1) s += __shfl_down(s, off, 64);
                if ((tid & 63) == 0) red[tid >> 6] = s;
                __syncthreads();
                if (tid == 0) vd[row] = red[0] + red[1] + red[2] + red[3] + bv[j];
                __syncthreads();   // protect red before next iteration
            } else {
                int i = (vb - M) * 256 + tid;
                const float* src = (i < n4w) ? Wq_ : Wk_;
                float4 v = reinterpret_cast<const float4*>(src)[i - (i < n4w ? 0 : n4w)];
                union { unsigned short s4[4]; uint2 u; } o;
                o.s4[0] = f2bf(v.x); o.s4[1] = f2bf(v.y); o.s4[2] = f2bf(v.z); o.s4[3] = f2bf(v.w);
                reinterpret_cast<uint2*>(wqk)[i] = o.u;
            }
        }
    }
    gbar(&bar[0]);

    // ================= phase B: q/k GEMM, 128x128, BK=64, dbuf, swizzled =================
    {
        unsigned short (*lA)[128 * 64] = (unsigned short (*)[128 * 64])(smem);
        unsigned short (*lB)[128 * 64] = (unsigned short (*)[128 * 64])(smem + 32768);

        const int bx = bid & 15, by = bid >> 4;
        const int wid = tid >> 6;
        const int wr = wid >> 1, wc = wid & 1;
        const int tileM = by * 128, tileN = bx * 128;

        const int srow = tid >> 3;
        const int scolL = (tid & 7) * 8;
        const int scolG = ((tid & 7) ^ (srow & 7)) * 8;
        const int frow = lane & 15;
        const int fq = lane >> 4;
        const int fsw = frow & 7;

        f32x4 acc[4][4];
        #pragma unroll
        for (int m = 0; m < 4; ++m)
            #pragma unroll
            for (int n = 0; n < 4; ++n)
                acc[m][n] = (f32x4){0.f, 0.f, 0.f, 0.f};

        auto stage = [&](int buf, int k0) {
            #pragma unroll
            for (int j = 0; j < 4; ++j) {
                int r = j * 32 + srow;
                g2lds16(xb + (size_t)(tileM + r) * K + (k0 + scolG),  &lA[buf][r * 64 + scolL]);
                g2lds16(wqk + (size_t)(tileN + r) * K + (k0 + scolG), &lB[buf][r * 64 + scolL]);
            }
        };

        stage(0, 0);
        __syncthreads();
        int cur = 0;
        for (int k0 = 0; k0 < K; k0 += 64) {
            if (k0 + 64 < K) stage(cur ^ 1, k0 + 64);

            #pragma unroll
            for (int kk = 0; kk < 2; ++kk) {
                const int g = ((kk * 4 + fq) ^ fsw) * 8;
                bf16x8 af[4], bfr[4];
                #pragma unroll
                for (int m = 0; m < 4; ++m)
                    af[m] = *reinterpret_cast<const bf16x8*>(
                        &lA[cur][(wr * 64 + m * 16 + frow) * 64 + g]);
                #pragma unroll
                for (int n = 0; n < 4; ++n)
                    bfr[n] = *reinterpret_cast<const bf16x8*>(
                        &lB[cur][(wc * 64 + n * 16 + frow) * 64 + g]);

                #pragma unroll
                for (int m = 0; m < 4; ++m)
                    #pragma unroll
                    for (int n = 0; n < 4; ++n)
                        acc[m][n] = __builtin_amdgcn_mfma_f32_16x16x32_bf16(af[m], bfr[n], acc[m][n], 0, 0, 0);
            }

            __syncthreads();
            cur ^= 1;
        }

        const int orow = (lane >> 4) * 4;
        const int ocol = lane & 15;
        const bool isQ = tileN < 1024;
        unsigned short* Cq = isQ ? qb : kb;
        const float* bias = isQ ? bq : bk;
        const int cb = tileN - (isQ ? 0 : 1024);

        #pragma unroll
        for (int n = 0; n < 4; ++n) {
            int col = cb + wc * 64 + n * 16 + ocol;
            float bia = bias[col];
            #pragma unroll
            for (int m = 0; m < 4; ++m) {
                #pragma unroll
                for (int i = 0; i < 4; ++i) {
                    int row = tileM + wr * 64 + m * 16 + orow + i;
                    float v = acc[m][n][i] + bia;
                    Cq[(size_t)row * 1024 + col] = f2bf(v > 0.f ? v : 0.f);
                }
            }
        }
    }
    gbar(&bar[1]);

    // ================= phase C: QK GEMM, 64x128, BK=64, swizzled, fused epilogue =================
    {
        unsigned short (*lA)[64 * 64]  = (unsigned short (*)[64 * 64])(smem);
        unsigned short (*lB)[128 * 64] = (unsigned short (*)[128 * 64])(smem + 16384);

        const int bx = bid & 7, by = (bid >> 3) & 15, bz = bid >> 7;
        const int wid = tid >> 6;
        const int wr = wid >> 1, wc = wid & 1;
        const int tileM = by * 64, tileN = bx * 128;

        const unsigned short* Ab = qb + (size_t)bz * 1024 * 1024;
        const unsigned short* Bb = kb + (size_t)bz * 1024 * 1024;

        const int srow = tid >> 3;
        const int scolL = (tid & 7) * 8;
        const int scolG = ((tid & 7) ^ (srow & 7)) * 8;
        const int frow = lane & 15;
        const int fq = lane >> 4;
        const int fsw = frow & 7;

        f32x4 acc[2][4];
        #pragma unroll
        for (int m = 0; m < 2; ++m)
            #pragma unroll
            for (int n = 0; n < 4; ++n)
                acc[m][n] = (f32x4){0.f, 0.f, 0.f, 0.f};

        auto stage = [&](int buf, int k0) {
            #pragma unroll
            for (int j = 0; j < 2; ++j) {
                int r = j * 32 + srow;
                g2lds16(Ab + (size_t)(tileM + r) * K + (k0 + scolG), &lA[buf][r * 64 + scolL]);
            }
            #pragma unroll
            for (int j = 0; j < 4; ++j) {
                int r = j * 32 + srow;
                g2lds16(Bb + (size_t)(tileN + r) * K + (k0 + scolG), &lB[buf][r * 64 + scolL]);
            }
        };

        stage(0, 0);
        __syncthreads();
        int cur = 0;
        for (int k0 = 0; k0 < K; k0 += 64) {
            if (k0 + 64 < K) stage(cur ^ 1, k0 + 64);

            #pragma unroll
            for (int kk = 0; kk < 2; ++kk) {
                const int g = ((kk * 4 + fq) ^ fsw) * 8;
                bf16x8 af[2], bfr[4];
                #pragma unroll
                for (int m = 0; m < 2; ++m)
                    af[m] = *reinterpret_cast<const bf16x8*>(
                        &lA[cur][(wr * 32 + m * 16 + frow) * 64 + g]);
                #pragma unroll
                for (int n = 0; n < 4; ++n)
                    bfr[n] = *reinterpret_cast<const bf16x8*>(
                        &lB[cur][(wc * 64 + n * 16 + frow) * 64 + g]);

                #pragma unroll
                for (int m = 0; m < 2; ++m)
                    #pragma unroll
                    for (int n = 0; n < 4; ++n)
                        acc[m][n] = __builtin_amdgcn_mfma_f32_16x16x32_bf16(af[m], bfr[n], acc[m][n], 0, 0, 0);
            }

            __syncthreads();
            cur ^= 1;
        }

        const int orow = (lane >> 4) * 4;
        const int ocol = lane & 15;

        unsigned short* ob = nmb + (size_t)bz * 1024 * 1024;
        const float* vdb = vd + bz * 1024;
        const float g = gammap[0];
        const float l2g = log2f(g);
        const float inv1mg = 1.f / (1.f - g);
        const float c1 = g * inv1mg;

        int jcol[4]; float gj[4], vdv[4];
        #pragma unroll
        for (int n = 0; n < 4; ++n) {
            jcol[n] = tileN + wc * 64 + n * 16 + ocol;
            gj[n] = exp2f((float)jcol[n] * l2g);
            vdv[n] = vdb[jcol[n]];
        }

        #pragma unroll
        for (int m = 0; m < 2; ++m) {
            #pragma unroll
            for (int i = 0; i < 4; ++i) {
                int t = tileM + wr * 32 + m * 16 + orow + i;
                float gt = exp2f((float)t * l2g);
                float ctf = (1.f - g * gt) * inv1mg;
                float s = 0.f;
                #pragma unroll
                for (int n = 0; n < 4; ++n) {
                    int j = jcol[n];
                    float Cfut = exp2f((float)(j - t) * l2g) * ctf;        // j > t
                    float Cpast = (float)(t - j + 1) + c1 * (1.f - gj[n]); // j <= t
                    float Cw = (j <= t) ? Cpast : Cfut;
                    float v = acc[m][n][i];
                    s += Cw * v;
                    ob[(size_t)t * 1024 + j] = f2bf(Cw * vdv[n] * v);
                }
                s += __shfl_xor(s, 1, 64);
                s += __shfl_xor(s, 2, 64);
                s += __shfl_xor(s, 4, 64);
                s += __shfl_xor(s, 8, 64);
                if ((lane & 15) == 0)
                    dpart[(size_t)(bx * 2 + wc) * M + bz * 1024 + t] = s;
            }
        }
    }
    gbar(&bar[2]);

    // ================= phase D: out = num' / denom (8 rows per block) =================
    {
        #pragma unroll
        for (int e = 0; e < 8; ++e) {
            int r = bid * 8 + e;
            float s = 1e-6f;
            #pragma unroll
            for (int p = 0; p < 16; ++p) s += dpart[(size_t)p * M + r];
            float inv = 1.f / s;
            uint2 u = reinterpret_cast<const uint2*>(nmb + (size_t)r * 1024)[tid];
            float4 v = { bf2f((unsigned short)(u.x & 0xffff)) * inv,
                         bf2f((unsigned short)(u.x >> 16))    * inv,
                         bf2f((unsigned short)(u.y & 0xffff)) * inv,
                         bf2f((unsigned short)(u.y >> 16))    * inv };
            reinterpret_cast<float4*>(out + (size_t)r * 1024)[tid] = v;
        }
    }
}

// ---------- launch ----------

extern "C" void kernel_launch(void* const* d_in, const int* in_sizes, int n_in,
                              void* d_out, int out_size, void* d_ws, size_t ws_size,
                              hipStream_t stream) {
    const float* x     = (const float*)d_in[0];
    const float* gamma = (const float*)d_in[1];
    const float* Wq    = (const float*)d_in[2];
    const float* bq    = (const float*)d_in[3];
    const float* Wk    = (const float*)d_in[4];
    const float* bk    = (const float*)d_in[5];
    const float* Wv    = (const float*)d_in[6];
    const float* bv    = (const float*)d_in[7];
    float* out = (float*)d_out;

    const int D = 1024, T = 1024;
    const int B = in_sizes[0] / (T * D);
    const int M = B * T;  // 4096

    char* ws = (char*)d_ws;
    size_t off = 0;
    unsigned short* xb  = (unsigned short*)(ws + off); off += (size_t)M * D * 2;      // 8 MB
    unsigned short* wqk = (unsigned short*)(ws + off); off += (size_t)2 * D * D * 2;  // 4 MB
    unsigned short* qb  = (unsigned short*)(ws + off); off += (size_t)M * D * 2;      // 8 MB
    unsigned short* kb  = (unsigned short*)(ws + off); off += (size_t)M * D * 2;      // 8 MB
    float* vd    = (float*)(ws + off); off += (size_t)M * 4;                          // 16 KB
    float* dpart = (float*)(ws + off); off += (size_t)16 * M * 4;                     // 256 KB
    int* bar     = (int*)(ws + off);   off += 3 * 4;

    const int n4w = D * D / 4;

    // zero the 3 phase-barrier counters (graph-capture-safe, per-replay)
    hipMemsetAsync(bar, 0, 3 * sizeof(int), stream);

    fused_kernel<<<dim3(NB), dim3(256), 0, stream>>>(
        x, Wq, Wk, Wv, bv, bq, bk, gamma,
        xb, wqk, qb, kb, vd, dpart, out, bar, M, n4w);
}

// Round 22
// 63.655 us; speedup vs baseline: 4.3424x; 4.3424x over previous
//
#include <hip/hip_runtime.h>

typedef __attribute__((ext_vector_type(8))) short bf16x8;
typedef __attribute__((ext_vector_type(4))) float f32x4;

// ---------- helpers ----------

__device__ __forceinline__ unsigned short f2bf(float f) {
    unsigned int u = __builtin_bit_cast(unsigned int, f);
    u += 0x7fffu + ((u >> 16) & 1u);
    return (unsigned short)(u >> 16);
}

__device__ __forceinline__ float bf2f(unsigned short s) {
    return __builtin_bit_cast(float, (unsigned int)s << 16);
}

__device__ __forceinline__ void g2lds16(const unsigned short* g, unsigned short* l) {
    __builtin_amdgcn_global_load_lds(
        (const __attribute__((address_space(1))) unsigned int*)g,
        (__attribute__((address_space(3))) unsigned int*)l, 16, 0, 0);
}

// ---------- prep: pack x/Wq/Wk -> bf16; vdiag fused into the x-pack blocks ----------

__global__ __launch_bounds__(256)
void prep_kernel(const float* __restrict__ x, const float* __restrict__ wq,
                 const float* __restrict__ wk, const float* __restrict__ Wv,
                 const float* __restrict__ bv, unsigned short* __restrict__ xb,
                 unsigned short* __restrict__ wqk, float* __restrict__ vd,
                 int M, int n4w) {
    const int tid = threadIdx.x;
    if ((int)blockIdx.x < M) {
        const int row = blockIdx.x;          // b*1024 + j
        const int j = row & 1023;
        const int e4 = row * 256 + tid;      // float4 index into x
        float4 v = reinterpret_cast<const float4*>(x)[e4];
        union { unsigned short s[4]; uint2 u; } o;
        o.s[0] = f2bf(v.x); o.s[1] = f2bf(v.y); o.s[2] = f2bf(v.z); o.s[3] = f2bf(v.w);
        reinterpret_cast<uint2*>(xb)[e4] = o.u;

        float4 w = reinterpret_cast<const float4*>(Wv + (size_t)j * 1024)[tid];
        float s = v.x * w.x + v.y * w.y + v.z * w.z + v.w * w.w;
        #pragma unroll
        for (int off = 32; off; off >>= 1) s += __shfl_down(s, off, 64);
        __shared__ float red[4];
        if ((tid & 63) == 0) red[tid >> 6] = s;
        __syncthreads();
        if (tid == 0) vd[row] = red[0] + red[1] + red[2] + red[3] + bv[j];
    } else {
        int i = (blockIdx.x - M) * 256 + tid;
        const float* src;
        if (i < n4w) { src = wq; }
        else         { src = wk; }
        float4 v = reinterpret_cast<const float4*>(src)[i - (i < n4w ? 0 : n4w)];
        union { unsigned short s[4]; uint2 u; } o;
        o.s[0] = f2bf(v.x); o.s[1] = f2bf(v.y); o.s[2] = f2bf(v.z); o.s[3] = f2bf(v.w);
        reinterpret_cast<uint2*>(wqk)[i] = o.u;
    }
}

// ---------- q/k GEMM: 128x128 tile, BK=64, dbuf, 4x4 acc, swizzled ----------

__global__ __launch_bounds__(256, 2)
void gemm_qk_kernel(const unsigned short* __restrict__ A, const unsigned short* __restrict__ Bm,
                    unsigned short* __restrict__ qb, unsigned short* __restrict__ kb,
                    const float* __restrict__ bq, const float* __restrict__ bk, int K) {
    __shared__ unsigned short lA[2][128 * 64];   // 16 KB x2
    __shared__ unsigned short lB[2][128 * 64];   // 16 KB x2

    const int tid = threadIdx.x;
    const int lane = tid & 63;
    const int wid = tid >> 6;
    const int wr = wid >> 1;
    const int wc = wid & 1;
    const int tileM = blockIdx.y * 128, tileN = blockIdx.x * 128;

    const int srow = tid >> 3;                       // 0..31
    const int scolL = (tid & 7) * 8;                 // linear LDS granule (dest)
    const int scolG = ((tid & 7) ^ (srow & 7)) * 8;  // swizzled global granule (src)
    const int frow = lane & 15;
    const int fq = lane >> 4;                        // 0..3
    const int fsw = frow & 7;

    f32x4 acc[4][4];
    #pragma unroll
    for (int m = 0; m < 4; ++m)
        #pragma unroll
        for (int n = 0; n < 4; ++n)
            acc[m][n] = (f32x4){0.f, 0.f, 0.f, 0.f};

    auto stage = [&](int buf, int k0) {   // 8 gld16 per thread
        #pragma unroll
        for (int j = 0; j < 4; ++j) {
            int r = j * 32 + srow;
            g2lds16(A + (size_t)(tileM + r) * K + (k0 + scolG),  &lA[buf][r * 64 + scolL]);
            g2lds16(Bm + (size_t)(tileN + r) * K + (k0 + scolG), &lB[buf][r * 64 + scolL]);
        }
    };

    stage(0, 0);
    __syncthreads();
    int cur = 0;
    for (int k0 = 0; k0 < K; k0 += 64) {
        if (k0 + 64 < K) stage(cur ^ 1, k0 + 64);

        #pragma unroll
        for (int kk = 0; kk < 2; ++kk) {
            const int g = ((kk * 4 + fq) ^ fsw) * 8;   // swizzled read granule
            bf16x8 af[4], bfr[4];
            #pragma unroll
            for (int m = 0; m < 4; ++m)
                af[m] = *reinterpret_cast<const bf16x8*>(
                    &lA[cur][(wr * 64 + m * 16 + frow) * 64 + g]);
            #pragma unroll
            for (int n = 0; n < 4; ++n)
                bfr[n] = *reinterpret_cast<const bf16x8*>(
                    &lB[cur][(wc * 64 + n * 16 + frow) * 64 + g]);

            #pragma unroll
            for (int m = 0; m < 4; ++m)
                #pragma unroll
                for (int n = 0; n < 4; ++n)
                    acc[m][n] = __builtin_amdgcn_mfma_f32_16x16x32_bf16(af[m], bfr[n], acc[m][n], 0, 0, 0);
        }

        __syncthreads();
        cur ^= 1;
    }

    const int orow = (lane >> 4) * 4;
    const int ocol = lane & 15;
    const bool isQ = tileN < 1024;
    unsigned short* Cq = isQ ? qb : kb;
    const float* bias = isQ ? bq : bk;
    const int cb = tileN - (isQ ? 0 : 1024);

    #pragma unroll
    for (int n = 0; n < 4; ++n) {
        int col = cb + wc * 64 + n * 16 + ocol;
        float bia = bias[col];
        #pragma unroll
        for (int m = 0; m < 4; ++m) {
            #pragma unroll
            for (int i = 0; i < 4; ++i) {
                int row = tileM + wr * 64 + m * 16 + orow + i;
                float v = acc[m][n][i] + bia;
                Cq[(size_t)row * 1024 + col] = f2bf(v > 0.f ? v : 0.f);
            }
        }
    }
}

// ---------- QK GEMM (per batch), 64x128 tile, BK=64, swizzled, fused epilogue ----------

__global__ __launch_bounds__(256, 3)
void gemm_attn_kernel(const unsigned short* __restrict__ A, const unsigned short* __restrict__ Bm,
                      unsigned short* __restrict__ nmb, const float* __restrict__ vd,
                      float* __restrict__ dpart, const float* __restrict__ gammap,
                      int K, int Mtot) {
    __shared__ unsigned short lA[2][64 * 64];    //  8 KB x2
    __shared__ unsigned short lB[2][128 * 64];   // 16 KB x2

    const int tid = threadIdx.x;
    const int lane = tid & 63;
    const int wid = tid >> 6;
    const int wr = wid >> 1, wc = wid & 1;
    const int tileM = blockIdx.y * 64, tileN = blockIdx.x * 128;

    const unsigned short* Ab = A + (size_t)blockIdx.z * 1024 * 1024;
    const unsigned short* Bb = Bm + (size_t)blockIdx.z * 1024 * 1024;

    const int srow = tid >> 3;                       // 0..31
    const int scolL = (tid & 7) * 8;
    const int scolG = ((tid & 7) ^ (srow & 7)) * 8;
    const int frow = lane & 15;
    const int fq = lane >> 4;
    const int fsw = frow & 7;

    f32x4 acc[2][4];
    #pragma unroll
    for (int m = 0; m < 2; ++m)
        #pragma unroll
        for (int n = 0; n < 4; ++n)
            acc[m][n] = (f32x4){0.f, 0.f, 0.f, 0.f};

    auto stage = [&](int buf, int k0) {   // 6 gld16 per thread
        #pragma unroll
        for (int j = 0; j < 2; ++j) {
            int r = j * 32 + srow;
            g2lds16(Ab + (size_t)(tileM + r) * K + (k0 + scolG), &lA[buf][r * 64 + scolL]);
        }
        #pragma unroll
        for (int j = 0; j < 4; ++j) {
            int r = j * 32 + srow;
            g2lds16(Bb + (size_t)(tileN + r) * K + (k0 + scolG), &lB[buf][r * 64 + scolL]);
        }
    };

    stage(0, 0);
    __syncthreads();
    int cur = 0;
    for (int k0 = 0; k0 < K; k0 += 64) {
        if (k0 + 64 < K) stage(cur ^ 1, k0 + 64);

        #pragma unroll
        for (int kk = 0; kk < 2; ++kk) {
            const int g = ((kk * 4 + fq) ^ fsw) * 8;
            bf16x8 af[2], bfr[4];
            #pragma unroll
            for (int m = 0; m < 2; ++m)
                af[m] = *reinterpret_cast<const bf16x8*>(
                    &lA[cur][(wr * 32 + m * 16 + frow) * 64 + g]);
            #pragma unroll
            for (int n = 0; n < 4; ++n)
                bfr[n] = *reinterpret_cast<const bf16x8*>(
                    &lB[cur][(wc * 64 + n * 16 + frow) * 64 + g]);

            #pragma unroll
            for (int m = 0; m < 2; ++m)
                #pragma unroll
                for (int n = 0; n < 4; ++n)
                    acc[m][n] = __builtin_amdgcn_mfma_f32_16x16x32_bf16(af[m], bfr[n], acc[m][n], 0, 0, 0);
        }

        __syncthreads();
        cur ^= 1;
    }

    const int orow = (lane >> 4) * 4;
    const int ocol = lane & 15;

    unsigned short* ob = nmb + (size_t)blockIdx.z * 1024 * 1024;
    const float* vdb = vd + blockIdx.z * 1024;
    const float g = gammap[0];
    const float l2g = log2f(g);
    const float inv1mg = 1.f / (1.f - g);
    const float c1 = g * inv1mg;

    int jcol[4]; float gj[4], vdv[4];
    #pragma unroll
    for (int n = 0; n < 4; ++n) {
        jcol[n] = tileN + wc * 64 + n * 16 + ocol;
        gj[n] = exp2f((float)jcol[n] * l2g);
        vdv[n] = vdb[jcol[n]];
    }

    #pragma unroll
    for (int m = 0; m < 2; ++m) {
        #pragma unroll
        for (int i = 0; i < 4; ++i) {
            int t = tileM + wr * 32 + m * 16 + orow + i;
            float gt = exp2f((float)t * l2g);
            float ctf = (1.f - g * gt) * inv1mg;
            float s = 0.f;
            #pragma unroll
            for (int n = 0; n < 4; ++n) {
                int j = jcol[n];
                float Cfut = exp2f((float)(j - t) * l2g) * ctf;        // j > t
                float Cpast = (float)(t - j + 1) + c1 * (1.f - gj[n]); // j <= t
                float Cw = (j <= t) ? Cpast : Cfut;
                float v = acc[m][n][i];
                s += Cw * v;
                ob[(size_t)t * 1024 + j] = f2bf(Cw * vdv[n] * v);
            }
            s += __shfl_xor(s, 1, 64);
            s += __shfl_xor(s, 2, 64);
            s += __shfl_xor(s, 4, 64);
            s += __shfl_xor(s, 8, 64);
            if ((lane & 15) == 0)
                dpart[(size_t)(blockIdx.x * 2 + wc) * Mtot + blockIdx.z * 1024 + t] = s;
        }
    }
}

// ---------- out[r,:] = bf16 num'[r,:] / (eps + sum_p dpart[p][r]) ----------

__global__ __launch_bounds__(256)
void scale_kernel(const unsigned short* __restrict__ nmb, float* __restrict__ out,
                  const float* __restrict__ dpart, int Mtot) {
    int r = blockIdx.x;
    float s = 1e-6f;
    #pragma unroll
    for (int p = 0; p < 16; ++p) s += dpart[(size_t)p * Mtot + r];
    float inv = 1.f / s;
    const uint2* src = reinterpret_cast<const uint2*>(nmb + (size_t)r * 1024);
    float4* dst = reinterpret_cast<float4*>(out + (size_t)r * 1024);
    uint2 u = src[threadIdx.x];
    float4 v = { bf2f((unsigned short)(u.x & 0xffff)) * inv,
                 bf2f((unsigned short)(u.x >> 16))    * inv,
                 bf2f((unsigned short)(u.y & 0xffff)) * inv,
                 bf2f((unsigned short)(u.y >> 16))    * inv };
    dst[threadIdx.x] = v;
}

// ---------- launch ----------

extern "C" void kernel_launch(void* const* d_in, const int* in_sizes, int n_in,
                              void* d_out, int out_size, void* d_ws, size_t ws_size,
                              hipStream_t stream) {
    const float* x     = (const float*)d_in[0];
    const float* gamma = (const float*)d_in[1];
    const float* Wq    = (const float*)d_in[2];
    const float* bq    = (const float*)d_in[3];
    const float* Wk    = (const float*)d_in[4];
    const float* bk    = (const float*)d_in[5];
    const float* Wv    = (const float*)d_in[6];
    const float* bv    = (const float*)d_in[7];
    float* out = (float*)d_out;

    const int D = 1024, T = 1024;
    const int B = in_sizes[0] / (T * D);
    const int M = B * T;  // 4096

    char* ws = (char*)d_ws;
    size_t off = 0;
    unsigned short* xb  = (unsigned short*)(ws + off); off += (size_t)M * D * 2;      // 8 MB
    unsigned short* wqk = (unsigned short*)(ws + off); off += (size_t)2 * D * D * 2;  // 4 MB
    unsigned short* qb  = (unsigned short*)(ws + off); off += (size_t)M * D * 2;      // 8 MB
    unsigned short* kb  = (unsigned short*)(ws + off); off += (size_t)M * D * 2;      // 8 MB
    float* vd    = (float*)(ws + off); off += (size_t)M * 4;                          // 16 KB
    float* dpart = (float*)(ws + off); off += (size_t)16 * M * 4;                     // 256 KB
    unsigned short* nmb = xb;  // xb dead after gemm_qk; reuse as bf16 num' scratch

    const int n4w = D * D / 4;

    // 1. prep: pack x (+fused vdiag per row) and Wq/Wk
    prep_kernel<<<dim3(M + 2 * n4w / 256), 256, 0, stream>>>(
        x, Wq, Wk, Wv, bv, xb, wqk, vd, M, n4w);

    // 2. q/k GEMM; 128x128 tiles, BK=64, dbuf, swizzled
    gemm_qk_kernel<<<dim3(2048 / 128, M / 128), 256, 0, stream>>>(
        xb, wqk, qb, kb, bq, bk, D);

    // 3. QK GEMM fused epilogue; 64x128 tiles, BK=64, dbuf, swizzled
    gemm_attn_kernel<<<dim3(T / 128, T / 64, B), 256, 0, stream>>>(
        qb, kb, nmb, vd, dpart, gamma, D, M);

    // 4. out = num' / denom
    scale_kernel<<<dim3(M), 256, 0, stream>>>(nmb, out, dpart, M);
}